// Round 1
// baseline (2205.547 us; speedup 1.0000x reference)
//
#include <hip/hip_runtime.h>
#include <stdint.h>
#include <math.h>

#define NE 8
#define NT 8192
#define NH 1024
#define NI 4096
#define BM 128
#define BK 32

typedef _Float16 half8 __attribute__((ext_vector_type(8)));
typedef float f32x4 __attribute__((ext_vector_type(4)));

// ---------------- workspace layout (ints at base) ----------------
// [0..8)   cnt        [8..17)  off      [17..25) cursor    [25..34) mbcum
// int 64 .. : te[NT*2]        (token-major expert ids)
// int 64+NT*2 : tw[NT*2]      (float weights)
// int 64+NT*4 : tok_slot[NT*2]
// int 64+NT*6 : w_slot[NT*2]  (float)
// byte 512KiB : x16 (NT*NH f16, 16 MiB)
// byte 18MiB  : act (NT*2*NI f16, 128 MiB)
// total ~146 MiB

__device__ __forceinline__ half8 pack_half8(float4 a, float4 b) {
  half8 h;
  h[0] = (_Float16)a.x; h[1] = (_Float16)a.y; h[2] = (_Float16)a.z; h[3] = (_Float16)a.w;
  h[4] = (_Float16)b.x; h[5] = (_Float16)b.y; h[6] = (_Float16)b.z; h[7] = (_Float16)b.w;
  return h;
}

// ---------------- router: logits, softmax-top2, counts, x->f16 ----------------
__global__ __launch_bounds__(256) void moe_router(
    const float* __restrict__ x, const float* __restrict__ rw,
    int* __restrict__ iws, _Float16* __restrict__ x16)
{
  int wid  = threadIdx.x >> 6;
  int lane = threadIdx.x & 63;
  int t = (blockIdx.x << 2) + wid;  // one wave per token

  const float4* xp4 = (const float4*)(x + (size_t)t * NH + lane * 16);
  float xv[16];
  #pragma unroll
  for (int j = 0; j < 4; ++j) {
    float4 v = xp4[j];
    xv[4*j+0] = v.x; xv[4*j+1] = v.y; xv[4*j+2] = v.z; xv[4*j+3] = v.w;
  }
  // fused x -> f16
  half8 h0, h1;
  #pragma unroll
  for (int j = 0; j < 8; ++j) { h0[j] = (_Float16)xv[j]; h1[j] = (_Float16)xv[8+j]; }
  half8* xo = (half8*)(x16 + (size_t)t * NH + lane * 16);
  xo[0] = h0; xo[1] = h1;

  float lg[NE];
  #pragma unroll
  for (int e = 0; e < NE; ++e) {
    const float4* wp4 = (const float4*)(rw + e * NH + lane * 16);
    float s = 0.f;
    #pragma unroll
    for (int j = 0; j < 4; ++j) {
      float4 w = wp4[j];
      s += xv[4*j+0]*w.x + xv[4*j+1]*w.y + xv[4*j+2]*w.z + xv[4*j+3]*w.w;
    }
    lg[e] = s;
  }
  #pragma unroll
  for (int d = 32; d > 0; d >>= 1) {
    #pragma unroll
    for (int e = 0; e < NE; ++e) lg[e] += __shfl_xor(lg[e], d, 64);
  }
  if (lane == 0) {
    int e0 = 0;
    #pragma unroll
    for (int e = 1; e < NE; ++e) if (lg[e] > lg[e0]) e0 = e;   // first max (tie -> low idx)
    int e1 = (e0 == 0) ? 1 : 0;
    #pragma unroll
    for (int e = 0; e < NE; ++e) if (e != e0 && lg[e] > lg[e1]) e1 = e;
    // normalized top-2 softmax weights: w0 = 1/(1+exp(l1-l0))
    float p1 = expf(lg[e1] - lg[e0]);
    float s  = 1.f + p1;
    int*   te = iws + 64;
    float* tw = (float*)(iws + 64 + NT*2);
    te[2*t]   = e0; te[2*t+1] = e1;
    tw[2*t]   = 1.f / s; tw[2*t+1] = p1 / s;
    atomicAdd(iws + e0, 1);
    atomicAdd(iws + e1, 1);
  }
}

// ---------------- scan: offsets + padded m-block cumsum ----------------
__global__ void moe_scan(int* iws) {
  if (threadIdx.x == 0 && blockIdx.x == 0) {
    int* cnt = iws; int* off = iws + 8; int* mbc = iws + 25;
    int o = 0, m = 0;
    for (int e = 0; e < NE; ++e) {
      off[e] = o; mbc[e] = m;
      o += cnt[e]; m += (cnt[e] + BM - 1) / BM;
    }
    off[NE] = o; mbc[NE] = m;
  }
}

// ---------------- fill per-expert slot lists ----------------
__global__ __launch_bounds__(256) void moe_fill(int* __restrict__ iws) {
  int t = blockIdx.x * 256 + threadIdx.x;
  const int*   te = iws + 64;
  const float* tw = (const float*)(iws + 64 + NT*2);
  int*   cursor   = iws + 17;
  const int* off  = iws + 8;
  int*   tok_slot = iws + 64 + NT*4;
  float* w_slot   = (float*)(iws + 64 + NT*6);
  #pragma unroll
  for (int k = 0; k < 2; ++k) {
    int e = te[2*t+k];
    int pos = atomicAdd(&cursor[e], 1);
    int s = off[e] + pos;
    tok_slot[s] = t;
    w_slot[s]   = tw[2*t+k];
  }
}

// ---------------- GEMM1 + SiLU*up -> act (f16) ----------------
// block: 128 slot-rows x 128 i-cols; dual B tiles (gate rows i0+r, up rows NI+i0+r)
__global__ __launch_bounds__(256) void moe_gemm1(
    const _Float16* __restrict__ x16, const float* __restrict__ gup,
    const int* __restrict__ iws, _Float16* __restrict__ act)
{
  const int* cnt = iws; const int* off = iws + 8; const int* mbc = iws + 25;
  const int* tok_slot = iws + 64 + NT*4;
  int mb = blockIdx.x;
  if (mb >= mbc[NE]) return;
  int e = 0;
  while (mb >= mbc[e+1]) ++e;
  int mloc  = mb - mbc[e];
  int row0  = off[e] + mloc * BM;
  int nrows = cnt[e] - mloc * BM; if (nrows > BM) nrows = BM;
  int i0 = blockIdx.y * 128;

  __shared__ __align__(16) _Float16 Al [BM  * BK];
  __shared__ __align__(16) _Float16 Bgl[128 * BK];
  __shared__ __align__(16) _Float16 Bul[128 * BK];

  int tid = threadIdx.x;
  // A staging: 2 rows/thread, gathered via slot list (clamped for pad rows)
  int rA0 = tid >> 2, cg0 = (tid & 3) * 8;
  int rA1 = rA0 + 64;
  int sl0 = row0 + (rA0 < nrows ? rA0 : 0);
  int sl1 = row0 + (rA1 < nrows ? rA1 : 0);
  const _Float16* srcA0 = x16 + (size_t)tok_slot[sl0] * NH + cg0;
  const _Float16* srcA1 = x16 + (size_t)tok_slot[sl1] * NH + cg0;

  // B staging: 16 f32/thread per tile (gate + up), converted in regs
  int rB = tid >> 1, hB = (tid & 1) * 16;
  const float* srcBg = gup + ((size_t)e * 2 * NI + i0 + rB) * NH + hB;
  const float* srcBu = srcBg + (size_t)NI * NH;

  int wid = tid >> 6, lane = tid & 63;
  int wr = (wid >> 1) * 64, wc = (wid & 1) * 64;
  int fr = lane & 15, fq = lane >> 4;

  f32x4 accG[4][4] = {};
  f32x4 accU[4][4] = {};

  for (int k0 = 0; k0 < NH; k0 += BK) {
    __syncthreads();
    half8 a0 = *(const half8*)(srcA0 + k0);
    half8 a1 = *(const half8*)(srcA1 + k0);
    const float4* pg = (const float4*)(srcBg + k0);
    const float4* pu = (const float4*)(srcBu + k0);
    float4 g0 = pg[0], g1 = pg[1], g2 = pg[2], g3 = pg[3];
    float4 u0 = pu[0], u1 = pu[1], u2 = pu[2], u3 = pu[3];
    *(half8*)(Al + (size_t)tid * 8)         = a0;
    *(half8*)(Al + (size_t)(256 + tid) * 8) = a1;
    *(half8*)(Bgl + rB*BK + hB)     = pack_half8(g0, g1);
    *(half8*)(Bgl + rB*BK + hB + 8) = pack_half8(g2, g3);
    *(half8*)(Bul + rB*BK + hB)     = pack_half8(u0, u1);
    *(half8*)(Bul + rB*BK + hB + 8) = pack_half8(u2, u3);
    __syncthreads();

    half8 aF[4];
    #pragma unroll
    for (int m = 0; m < 4; ++m)
      aF[m] = *(const half8*)(Al + (wr + m*16 + fr)*BK + fq*8);
    #pragma unroll
    for (int n = 0; n < 4; ++n) {
      half8 bg = *(const half8*)(Bgl + (wc + n*16 + fr)*BK + fq*8);
      #pragma unroll
      for (int m = 0; m < 4; ++m)
        accG[m][n] = __builtin_amdgcn_mfma_f32_16x16x32_f16(aF[m], bg, accG[m][n], 0, 0, 0);
      half8 bu = *(const half8*)(Bul + (wc + n*16 + fr)*BK + fq*8);
      #pragma unroll
      for (int m = 0; m < 4; ++m)
        accU[m][n] = __builtin_amdgcn_mfma_f32_16x16x32_f16(aF[m], bu, accU[m][n], 0, 0, 0);
    }
  }

  // epilogue: act[slot][i0+c] = silu(g)*u   (C/D layout: col=lane&15, row=fq*4+j)
  #pragma unroll
  for (int m = 0; m < 4; ++m) {
    #pragma unroll
    for (int j = 0; j < 4; ++j) {
      int rl = wr + m*16 + fq*4 + j;
      if (rl < nrows) {
        _Float16* dst = act + (size_t)(row0 + rl) * NI + i0 + wc + fr;
        #pragma unroll
        for (int n = 0; n < 4; ++n) {
          float g = accG[m][n][j], u = accU[m][n][j];
          float a = (g / (1.f + __expf(-g))) * u;
          dst[n*16] = (_Float16)a;
        }
      }
    }
  }
}

// ---------------- GEMM2: y = act @ W2^T, scaled scatter-add to out ----------------
__global__ __launch_bounds__(256) void moe_gemm2(
    const _Float16* __restrict__ act, const float* __restrict__ dproj,
    const int* __restrict__ iws, float* __restrict__ out)
{
  const int* cnt = iws; const int* off = iws + 8; const int* mbc = iws + 25;
  const int* tok_slot = iws + 64 + NT*4;
  const float* w_slot = (const float*)(iws + 64 + NT*6);
  int mb = blockIdx.x;
  if (mb >= mbc[NE]) return;
  int e = 0;
  while (mb >= mbc[e+1]) ++e;
  int mloc  = mb - mbc[e];
  int row0  = off[e] + mloc * BM;
  int nrows = cnt[e] - mloc * BM; if (nrows > BM) nrows = BM;
  int h0 = blockIdx.y * 128;

  __shared__ __align__(16) _Float16 Al[BM  * BK];
  __shared__ __align__(16) _Float16 Bl[128 * BK];

  int tid = threadIdx.x;
  int rA0 = tid >> 2, cg0 = (tid & 3) * 8;
  int rA1 = rA0 + 64;
  const _Float16* srcA0 = act + (size_t)(row0 + (rA0 < nrows ? rA0 : 0)) * NI + cg0;
  const _Float16* srcA1 = act + (size_t)(row0 + (rA1 < nrows ? rA1 : 0)) * NI + cg0;
  int rB = tid >> 1, hB = (tid & 1) * 16;
  const float* srcB = dproj + ((size_t)e * NH + h0 + rB) * NI + hB;

  int wid = tid >> 6, lane = tid & 63;
  int wr = (wid >> 1) * 64, wc = (wid & 1) * 64;
  int fr = lane & 15, fq = lane >> 4;

  f32x4 acc[4][4] = {};

  for (int k0 = 0; k0 < NI; k0 += BK) {
    __syncthreads();
    half8 a0 = *(const half8*)(srcA0 + k0);
    half8 a1 = *(const half8*)(srcA1 + k0);
    const float4* pb = (const float4*)(srcB + k0);
    float4 b0 = pb[0], b1 = pb[1], b2 = pb[2], b3 = pb[3];
    *(half8*)(Al + (size_t)tid * 8)         = a0;
    *(half8*)(Al + (size_t)(256 + tid) * 8) = a1;
    *(half8*)(Bl + rB*BK + hB)     = pack_half8(b0, b1);
    *(half8*)(Bl + rB*BK + hB + 8) = pack_half8(b2, b3);
    __syncthreads();

    half8 aF[4];
    #pragma unroll
    for (int m = 0; m < 4; ++m)
      aF[m] = *(const half8*)(Al + (wr + m*16 + fr)*BK + fq*8);
    #pragma unroll
    for (int n = 0; n < 4; ++n) {
      half8 b = *(const half8*)(Bl + (wc + n*16 + fr)*BK + fq*8);
      #pragma unroll
      for (int m = 0; m < 4; ++m)
        acc[m][n] = __builtin_amdgcn_mfma_f32_16x16x32_f16(aF[m], b, acc[m][n], 0, 0, 0);
    }
  }

  #pragma unroll
  for (int m = 0; m < 4; ++m) {
    #pragma unroll
    for (int j = 0; j < 4; ++j) {
      int rl = wr + m*16 + fq*4 + j;
      if (rl < nrows) {
        int slot = row0 + rl;
        float wgt = w_slot[slot];
        int tok   = tok_slot[slot];
        float* dst = out + (size_t)tok * NH + h0 + wc + fr;
        #pragma unroll
        for (int n = 0; n < 4; ++n)
          atomicAdd(dst + n*16, acc[m][n][j] * wgt);
      }
    }
  }
}

extern "C" void kernel_launch(void* const* d_in, const int* in_sizes, int n_in,
                              void* d_out, int out_size, void* d_ws, size_t ws_size,
                              hipStream_t stream) {
  const float* x   = (const float*)d_in[0];
  const float* rw  = (const float*)d_in[1];
  const float* gup = (const float*)d_in[2];
  const float* dp  = (const float*)d_in[3];
  float* out = (float*)d_out;
  int* iws = (int*)d_ws;
  _Float16* x16 = (_Float16*)((char*)d_ws + (512u << 10));
  _Float16* act = (_Float16*)((char*)d_ws + (18u  << 20));

  hipMemsetAsync(d_out, 0, (size_t)NT * NH * sizeof(float), stream);
  hipMemsetAsync(d_ws, 0, 512, stream);

  moe_router<<<NT / 4, 256, 0, stream>>>(x, rw, iws, x16);
  moe_scan<<<1, 64, 0, stream>>>(iws);
  moe_fill<<<NT / 256, 256, 0, stream>>>(iws);

  dim3 g1(NT * 2 / BM + NE, NI / 128);  // 136 x 32, blockIdx.x fastest -> same B panel concurrent
  moe_gemm1<<<g1, 256, 0, stream>>>(x16, gup, iws, act);

  dim3 g2(NT * 2 / BM + NE, NH / 128);  // 136 x 8
  moe_gemm2<<<g2, 256, 0, stream>>>(act, dp, iws, out);
}

// Round 2
// 1305.976 us; speedup vs baseline: 1.6888x; 1.6888x over previous
//
#include <hip/hip_runtime.h>
#include <stdint.h>
#include <math.h>

#define NE 8
#define NT 8192
#define NH 1024
#define NI 4096
#define BM 128
#define BK 32

typedef _Float16 half8 __attribute__((ext_vector_type(8)));
typedef float f32x4 __attribute__((ext_vector_type(4)));

// ---------------- workspace layout ----------------
// ints at base: [0..8) cnt  [8..17) off  [17..25) cursor  [25..34) mbcum
// int 64..            : te[NT*2]
// int 64+NT*2         : tw[NT*2] (float)
// int 64+NT*4         : tok_slot[NT*2]
// int 64+NT*6         : w_slot[NT*2] (float)
// byte 0.5MiB : x16   (NT*NH f16, 16 MiB)
// byte 18MiB  : act   (NT*2*NI f16, 128 MiB)          -> ends 146 MiB (proven fits)
// byte 146MiB : gup16 (E*2*NI*NH f16, 128 MiB)        -> ends 274 MiB
// byte 274MiB : dp16  (E*NH*NI f16, 64 MiB)           -> ends 338 MiB
#define OFF_X16   (512u << 10)
#define OFF_ACT   (18u << 20)
#define OFF_GUP16 (146ull << 20)
#define OFF_DP16  (274ull << 20)
#define WS_NEED   (338ull << 20)

__device__ __forceinline__ half8 pack_half8(float4 a, float4 b) {
  half8 h;
  h[0] = (_Float16)a.x; h[1] = (_Float16)a.y; h[2] = (_Float16)a.z; h[3] = (_Float16)a.w;
  h[4] = (_Float16)b.x; h[5] = (_Float16)b.y; h[6] = (_Float16)b.z; h[7] = (_Float16)b.w;
  return h;
}

__device__ __forceinline__ void gload16(const void* g, void* l) {
  __builtin_amdgcn_global_load_lds(
      (const __attribute__((address_space(1))) uint32_t*)g,
      (__attribute__((address_space(3))) uint32_t*)l, 16, 0, 0);
}

// ---------------- weight convert f32 -> f16 ----------------
__global__ __launch_bounds__(256) void convert_w(
    const float* __restrict__ src, _Float16* __restrict__ dst, int n8)
{
  int stride = gridDim.x * 256;
  for (int i = blockIdx.x * 256 + threadIdx.x; i < n8; i += stride) {
    const float4* p = (const float4*)(src + (size_t)i * 8);
    float4 a = p[0], b = p[1];
    *(half8*)(dst + (size_t)i * 8) = pack_half8(a, b);
  }
}

// ---------------- router: logits, softmax-top2, counts, x->f16 ----------------
__global__ __launch_bounds__(256) void moe_router(
    const float* __restrict__ x, const float* __restrict__ rw,
    int* __restrict__ iws, _Float16* __restrict__ x16)
{
  int wid  = threadIdx.x >> 6;
  int lane = threadIdx.x & 63;
  int t = (blockIdx.x << 2) + wid;  // one wave per token

  const float4* xp4 = (const float4*)(x + (size_t)t * NH + lane * 16);
  float xv[16];
  #pragma unroll
  for (int j = 0; j < 4; ++j) {
    float4 v = xp4[j];
    xv[4*j+0] = v.x; xv[4*j+1] = v.y; xv[4*j+2] = v.z; xv[4*j+3] = v.w;
  }
  half8 h0, h1;
  #pragma unroll
  for (int j = 0; j < 8; ++j) { h0[j] = (_Float16)xv[j]; h1[j] = (_Float16)xv[8+j]; }
  half8* xo = (half8*)(x16 + (size_t)t * NH + lane * 16);
  xo[0] = h0; xo[1] = h1;

  float lg[NE];
  #pragma unroll
  for (int e = 0; e < NE; ++e) {
    const float4* wp4 = (const float4*)(rw + e * NH + lane * 16);
    float s = 0.f;
    #pragma unroll
    for (int j = 0; j < 4; ++j) {
      float4 w = wp4[j];
      s += xv[4*j+0]*w.x + xv[4*j+1]*w.y + xv[4*j+2]*w.z + xv[4*j+3]*w.w;
    }
    lg[e] = s;
  }
  #pragma unroll
  for (int d = 32; d > 0; d >>= 1) {
    #pragma unroll
    for (int e = 0; e < NE; ++e) lg[e] += __shfl_xor(lg[e], d, 64);
  }
  if (lane == 0) {
    int e0 = 0;
    #pragma unroll
    for (int e = 1; e < NE; ++e) if (lg[e] > lg[e0]) e0 = e;
    int e1 = (e0 == 0) ? 1 : 0;
    #pragma unroll
    for (int e = 0; e < NE; ++e) if (e != e0 && lg[e] > lg[e1]) e1 = e;
    float p1 = expf(lg[e1] - lg[e0]);
    float s  = 1.f + p1;
    int*   te = iws + 64;
    float* tw = (float*)(iws + 64 + NT*2);
    te[2*t]   = e0; te[2*t+1] = e1;
    tw[2*t]   = 1.f / s; tw[2*t+1] = p1 / s;
    atomicAdd(iws + e0, 1);
    atomicAdd(iws + e1, 1);
  }
}

// ---------------- scan ----------------
__global__ void moe_scan(int* iws) {
  if (threadIdx.x == 0 && blockIdx.x == 0) {
    int* cnt = iws; int* off = iws + 8; int* mbc = iws + 25;
    int o = 0, m = 0;
    for (int e = 0; e < NE; ++e) {
      off[e] = o; mbc[e] = m;
      o += cnt[e]; m += (cnt[e] + BM - 1) / BM;
    }
    off[NE] = o; mbc[NE] = m;
  }
}

// ---------------- fill slot lists ----------------
__global__ __launch_bounds__(256) void moe_fill(int* __restrict__ iws) {
  int t = blockIdx.x * 256 + threadIdx.x;
  const int*   te = iws + 64;
  const float* tw = (const float*)(iws + 64 + NT*2);
  int*   cursor   = iws + 17;
  const int* off  = iws + 8;
  int*   tok_slot = iws + 64 + NT*4;
  float* w_slot   = (float*)(iws + 64 + NT*6);
  #pragma unroll
  for (int k = 0; k < 2; ++k) {
    int e = te[2*t+k];
    int pos = atomicAdd(&cursor[e], 1);
    int s = off[e] + pos;
    tok_slot[s] = t;
    w_slot[s]   = tw[2*t+k];
  }
}

// =========== NEW: f16-weight GEMMs with global_load_lds + XOR swizzle ===========
// LDS tile [128][32] f16 (64B rows). Swizzle: 16B slot s' = s ^ ((row>>1)&3).
// global_load_lds writes linearly; the swizzle is applied on the per-lane global
// SOURCE address, and the same XOR on the ds_read side (rule #21).

__global__ __launch_bounds__(256) void moe_gemm1_f16(
    const _Float16* __restrict__ x16, const _Float16* __restrict__ gup16,
    const int* __restrict__ iws, _Float16* __restrict__ act)
{
  const int* cnt = iws; const int* off = iws + 8; const int* mbc = iws + 25;
  const int* tok_slot = iws + 64 + NT*4;
  int mb = blockIdx.x;
  if (mb >= mbc[NE]) return;
  int e = 0;
  while (mb >= mbc[e+1]) ++e;
  int mloc  = mb - mbc[e];
  int row0  = off[e] + mloc * BM;
  int nrows = cnt[e] - mloc * BM; if (nrows > BM) nrows = BM;
  int i0 = blockIdx.y * 128;

  __shared__ __align__(16) _Float16 Al [BM  * BK];
  __shared__ __align__(16) _Float16 Bgl[128 * BK];
  __shared__ __align__(16) _Float16 Bul[128 * BK];

  int tid = threadIdx.x, wid = tid >> 6, lane = tid & 63;
  // staging mapping: issue i covers rows (i*64 + wid*16) .. +16; lane -> (row, slot)
  int sr0 = wid*16 + (lane >> 2);
  int sr1 = 64 + sr0;
  int slot = lane & 3;
  int ks0 = (slot ^ ((sr0 >> 1) & 3)) * 8;   // swizzled source k-offset (elems)
  int ks1 = (slot ^ ((sr1 >> 1) & 3)) * 8;

  int tok0 = tok_slot[row0 + (sr0 < nrows ? sr0 : 0)];
  int tok1 = tok_slot[row0 + (sr1 < nrows ? sr1 : 0)];
  const _Float16* pA0  = x16 + (size_t)tok0 * NH + ks0;
  const _Float16* pA1  = x16 + (size_t)tok1 * NH + ks1;
  const _Float16* pBg0 = gup16 + ((size_t)e*2*NI + i0 + sr0) * NH + ks0;
  const _Float16* pBg1 = gup16 + ((size_t)e*2*NI + i0 + sr1) * NH + ks1;
  const _Float16* pBu0 = pBg0 + (size_t)NI * NH;
  const _Float16* pBu1 = pBg1 + (size_t)NI * NH;

  _Float16* dA0  = Al  + wid*512;       _Float16* dA1  = Al  + (4+wid)*512;
  _Float16* dBg0 = Bgl + wid*512;       _Float16* dBg1 = Bgl + (4+wid)*512;
  _Float16* dBu0 = Bul + wid*512;       _Float16* dBu1 = Bul + (4+wid)*512;

  int wr = (wid >> 1) * 64, wc = (wid & 1) * 64;
  int fr = lane & 15, fq = lane >> 4;

  f32x4 accG[4][4] = {};
  f32x4 accU[4][4] = {};

  for (int k0 = 0; k0 < NH; k0 += BK) {
    __syncthreads();
    gload16(pA0  + k0, dA0);
    gload16(pA1  + k0, dA1);
    gload16(pBg0 + k0, dBg0);
    gload16(pBg1 + k0, dBg1);
    gload16(pBu0 + k0, dBu0);
    gload16(pBu1 + k0, dBu1);
    asm volatile("s_waitcnt vmcnt(0)" ::: "memory");
    __syncthreads();

    half8 aF[4];
    #pragma unroll
    for (int m = 0; m < 4; ++m) {
      int r = wr + m*16 + fr;
      aF[m] = *(const half8*)(Al + r*BK + ((fq ^ ((r>>1)&3)) * 8));
    }
    #pragma unroll
    for (int n = 0; n < 4; ++n) {
      int rb = wc + n*16 + fr;
      int bo = rb*BK + ((fq ^ ((rb>>1)&3)) * 8);
      half8 bg = *(const half8*)(Bgl + bo);
      half8 bu = *(const half8*)(Bul + bo);
      #pragma unroll
      for (int m = 0; m < 4; ++m)
        accG[m][n] = __builtin_amdgcn_mfma_f32_16x16x32_f16(aF[m], bg, accG[m][n], 0, 0, 0);
      #pragma unroll
      for (int m = 0; m < 4; ++m)
        accU[m][n] = __builtin_amdgcn_mfma_f32_16x16x32_f16(aF[m], bu, accU[m][n], 0, 0, 0);
    }
  }

  #pragma unroll
  for (int m = 0; m < 4; ++m) {
    #pragma unroll
    for (int j = 0; j < 4; ++j) {
      int rl = wr + m*16 + fq*4 + j;
      if (rl < nrows) {
        _Float16* dst = act + (size_t)(row0 + rl) * NI + i0 + wc + fr;
        #pragma unroll
        for (int n = 0; n < 4; ++n) {
          float g = accG[m][n][j], u = accU[m][n][j];
          float a = (g / (1.f + __expf(-g))) * u;
          dst[n*16] = (_Float16)a;
        }
      }
    }
  }
}

__global__ __launch_bounds__(256) void moe_gemm2_f16(
    const _Float16* __restrict__ act, const _Float16* __restrict__ dp16,
    const int* __restrict__ iws, float* __restrict__ out)
{
  const int* cnt = iws; const int* off = iws + 8; const int* mbc = iws + 25;
  const int* tok_slot = iws + 64 + NT*4;
  const float* w_slot = (const float*)(iws + 64 + NT*6);
  int mb = blockIdx.x;
  if (mb >= mbc[NE]) return;
  int e = 0;
  while (mb >= mbc[e+1]) ++e;
  int mloc  = mb - mbc[e];
  int row0  = off[e] + mloc * BM;
  int nrows = cnt[e] - mloc * BM; if (nrows > BM) nrows = BM;
  int h0 = blockIdx.y * 128;

  __shared__ __align__(16) _Float16 Al[BM  * BK];
  __shared__ __align__(16) _Float16 Bl[128 * BK];

  int tid = threadIdx.x, wid = tid >> 6, lane = tid & 63;
  int sr0 = wid*16 + (lane >> 2);
  int sr1 = 64 + sr0;
  int slot = lane & 3;
  int ks0 = (slot ^ ((sr0 >> 1) & 3)) * 8;
  int ks1 = (slot ^ ((sr1 >> 1) & 3)) * 8;

  const _Float16* pA0 = act + (size_t)(row0 + (sr0 < nrows ? sr0 : 0)) * NI + ks0;
  const _Float16* pA1 = act + (size_t)(row0 + (sr1 < nrows ? sr1 : 0)) * NI + ks1;
  const _Float16* pB0 = dp16 + ((size_t)e*NH + h0 + sr0) * NI + ks0;
  const _Float16* pB1 = dp16 + ((size_t)e*NH + h0 + sr1) * NI + ks1;

  _Float16* dA0 = Al + wid*512;  _Float16* dA1 = Al + (4+wid)*512;
  _Float16* dB0 = Bl + wid*512;  _Float16* dB1 = Bl + (4+wid)*512;

  int wr = (wid >> 1) * 64, wc = (wid & 1) * 64;
  int fr = lane & 15, fq = lane >> 4;

  f32x4 acc[4][4] = {};

  for (int k0 = 0; k0 < NI; k0 += BK) {
    __syncthreads();
    gload16(pA0 + k0, dA0);
    gload16(pA1 + k0, dA1);
    gload16(pB0 + k0, dB0);
    gload16(pB1 + k0, dB1);
    asm volatile("s_waitcnt vmcnt(0)" ::: "memory");
    __syncthreads();

    half8 aF[4];
    #pragma unroll
    for (int m = 0; m < 4; ++m) {
      int r = wr + m*16 + fr;
      aF[m] = *(const half8*)(Al + r*BK + ((fq ^ ((r>>1)&3)) * 8));
    }
    #pragma unroll
    for (int n = 0; n < 4; ++n) {
      int rb = wc + n*16 + fr;
      half8 b = *(const half8*)(Bl + rb*BK + ((fq ^ ((rb>>1)&3)) * 8));
      #pragma unroll
      for (int m = 0; m < 4; ++m)
        acc[m][n] = __builtin_amdgcn_mfma_f32_16x16x32_f16(aF[m], b, acc[m][n], 0, 0, 0);
    }
  }

  #pragma unroll
  for (int m = 0; m < 4; ++m) {
    #pragma unroll
    for (int j = 0; j < 4; ++j) {
      int rl = wr + m*16 + fq*4 + j;
      if (rl < nrows) {
        int slotr = row0 + rl;
        float wgt = w_slot[slotr];
        int tok   = tok_slot[slotr];
        float* dst = out + (size_t)tok * NH + h0 + wc + fr;
        #pragma unroll
        for (int n = 0; n < 4; ++n)
          atomicAdd(dst + n*16, acc[m][n][j] * wgt);
      }
    }
  }
}

// =========== FALLBACK (R1 path): f32 weights, register staging ===========
__global__ __launch_bounds__(256) void moe_gemm1(
    const _Float16* __restrict__ x16, const float* __restrict__ gup,
    const int* __restrict__ iws, _Float16* __restrict__ act)
{
  const int* cnt = iws; const int* off = iws + 8; const int* mbc = iws + 25;
  const int* tok_slot = iws + 64 + NT*4;
  int mb = blockIdx.x;
  if (mb >= mbc[NE]) return;
  int e = 0;
  while (mb >= mbc[e+1]) ++e;
  int mloc  = mb - mbc[e];
  int row0  = off[e] + mloc * BM;
  int nrows = cnt[e] - mloc * BM; if (nrows > BM) nrows = BM;
  int i0 = blockIdx.y * 128;

  __shared__ __align__(16) _Float16 Al [BM  * BK];
  __shared__ __align__(16) _Float16 Bgl[128 * BK];
  __shared__ __align__(16) _Float16 Bul[128 * BK];

  int tid = threadIdx.x;
  int rA0 = tid >> 2, cg0 = (tid & 3) * 8;
  int rA1 = rA0 + 64;
  int sl0 = row0 + (rA0 < nrows ? rA0 : 0);
  int sl1 = row0 + (rA1 < nrows ? rA1 : 0);
  const _Float16* srcA0 = x16 + (size_t)tok_slot[sl0] * NH + cg0;
  const _Float16* srcA1 = x16 + (size_t)tok_slot[sl1] * NH + cg0;

  int rB = tid >> 1, hB = (tid & 1) * 16;
  const float* srcBg = gup + ((size_t)e * 2 * NI + i0 + rB) * NH + hB;
  const float* srcBu = srcBg + (size_t)NI * NH;

  int wid = tid >> 6, lane = tid & 63;
  int wr = (wid >> 1) * 64, wc = (wid & 1) * 64;
  int fr = lane & 15, fq = lane >> 4;

  f32x4 accG[4][4] = {};
  f32x4 accU[4][4] = {};

  for (int k0 = 0; k0 < NH; k0 += BK) {
    __syncthreads();
    half8 a0 = *(const half8*)(srcA0 + k0);
    half8 a1 = *(const half8*)(srcA1 + k0);
    const float4* pg = (const float4*)(srcBg + k0);
    const float4* pu = (const float4*)(srcBu + k0);
    float4 g0 = pg[0], g1 = pg[1], g2 = pg[2], g3 = pg[3];
    float4 u0 = pu[0], u1 = pu[1], u2 = pu[2], u3 = pu[3];
    *(half8*)(Al + (size_t)tid * 8)         = a0;
    *(half8*)(Al + (size_t)(256 + tid) * 8) = a1;
    *(half8*)(Bgl + rB*BK + hB)     = pack_half8(g0, g1);
    *(half8*)(Bgl + rB*BK + hB + 8) = pack_half8(g2, g3);
    *(half8*)(Bul + rB*BK + hB)     = pack_half8(u0, u1);
    *(half8*)(Bul + rB*BK + hB + 8) = pack_half8(u2, u3);
    __syncthreads();

    half8 aF[4];
    #pragma unroll
    for (int m = 0; m < 4; ++m)
      aF[m] = *(const half8*)(Al + (wr + m*16 + fr)*BK + fq*8);
    #pragma unroll
    for (int n = 0; n < 4; ++n) {
      half8 bg = *(const half8*)(Bgl + (wc + n*16 + fr)*BK + fq*8);
      #pragma unroll
      for (int m = 0; m < 4; ++m)
        accG[m][n] = __builtin_amdgcn_mfma_f32_16x16x32_f16(aF[m], bg, accG[m][n], 0, 0, 0);
      half8 bu = *(const half8*)(Bul + (wc + n*16 + fr)*BK + fq*8);
      #pragma unroll
      for (int m = 0; m < 4; ++m)
        accU[m][n] = __builtin_amdgcn_mfma_f32_16x16x32_f16(aF[m], bu, accU[m][n], 0, 0, 0);
    }
  }

  #pragma unroll
  for (int m = 0; m < 4; ++m) {
    #pragma unroll
    for (int j = 0; j < 4; ++j) {
      int rl = wr + m*16 + fq*4 + j;
      if (rl < nrows) {
        _Float16* dst = act + (size_t)(row0 + rl) * NI + i0 + wc + fr;
        #pragma unroll
        for (int n = 0; n < 4; ++n) {
          float g = accG[m][n][j], u = accU[m][n][j];
          float a = (g / (1.f + __expf(-g))) * u;
          dst[n*16] = (_Float16)a;
        }
      }
    }
  }
}

__global__ __launch_bounds__(256) void moe_gemm2(
    const _Float16* __restrict__ act, const float* __restrict__ dproj,
    const int* __restrict__ iws, float* __restrict__ out)
{
  const int* cnt = iws; const int* off = iws + 8; const int* mbc = iws + 25;
  const int* tok_slot = iws + 64 + NT*4;
  const float* w_slot = (const float*)(iws + 64 + NT*6);
  int mb = blockIdx.x;
  if (mb >= mbc[NE]) return;
  int e = 0;
  while (mb >= mbc[e+1]) ++e;
  int mloc  = mb - mbc[e];
  int row0  = off[e] + mloc * BM;
  int nrows = cnt[e] - mloc * BM; if (nrows > BM) nrows = BM;
  int h0 = blockIdx.y * 128;

  __shared__ __align__(16) _Float16 Al[BM  * BK];
  __shared__ __align__(16) _Float16 Bl[128 * BK];

  int tid = threadIdx.x;
  int rA0 = tid >> 2, cg0 = (tid & 3) * 8;
  int rA1 = rA0 + 64;
  const _Float16* srcA0 = act + (size_t)(row0 + (rA0 < nrows ? rA0 : 0)) * NI + cg0;
  const _Float16* srcA1 = act + (size_t)(row0 + (rA1 < nrows ? rA1 : 0)) * NI + cg0;
  int rB = tid >> 1, hB = (tid & 1) * 16;
  const float* srcB = dproj + ((size_t)e * NH + h0 + rB) * NI + hB;

  int wid = tid >> 6, lane = tid & 63;
  int wr = (wid >> 1) * 64, wc = (wid & 1) * 64;
  int fr = lane & 15, fq = lane >> 4;

  f32x4 acc[4][4] = {};

  for (int k0 = 0; k0 < NI; k0 += BK) {
    __syncthreads();
    half8 a0 = *(const half8*)(srcA0 + k0);
    half8 a1 = *(const half8*)(srcA1 + k0);
    const float4* pb = (const float4*)(srcB + k0);
    float4 b0 = pb[0], b1 = pb[1], b2 = pb[2], b3 = pb[3];
    *(half8*)(Al + (size_t)tid * 8)         = a0;
    *(half8*)(Al + (size_t)(256 + tid) * 8) = a1;
    *(half8*)(Bl + rB*BK + hB)     = pack_half8(b0, b1);
    *(half8*)(Bl + rB*BK + hB + 8) = pack_half8(b2, b3);
    __syncthreads();

    half8 aF[4];
    #pragma unroll
    for (int m = 0; m < 4; ++m)
      aF[m] = *(const half8*)(Al + (wr + m*16 + fr)*BK + fq*8);
    #pragma unroll
    for (int n = 0; n < 4; ++n) {
      half8 b = *(const half8*)(Bl + (wc + n*16 + fr)*BK + fq*8);
      #pragma unroll
      for (int m = 0; m < 4; ++m)
        acc[m][n] = __builtin_amdgcn_mfma_f32_16x16x32_f16(aF[m], b, acc[m][n], 0, 0, 0);
    }
  }

  #pragma unroll
  for (int m = 0; m < 4; ++m) {
    #pragma unroll
    for (int j = 0; j < 4; ++j) {
      int rl = wr + m*16 + fq*4 + j;
      if (rl < nrows) {
        int slot = row0 + rl;
        float wgt = w_slot[slot];
        int tok   = tok_slot[slot];
        float* dst = out + (size_t)tok * NH + h0 + wc + fr;
        #pragma unroll
        for (int n = 0; n < 4; ++n)
          atomicAdd(dst + n*16, acc[m][n][j] * wgt);
      }
    }
  }
}

extern "C" void kernel_launch(void* const* d_in, const int* in_sizes, int n_in,
                              void* d_out, int out_size, void* d_ws, size_t ws_size,
                              hipStream_t stream) {
  const float* x   = (const float*)d_in[0];
  const float* rw  = (const float*)d_in[1];
  const float* gup = (const float*)d_in[2];
  const float* dp  = (const float*)d_in[3];
  float* out = (float*)d_out;
  int* iws = (int*)d_ws;
  _Float16* x16   = (_Float16*)((char*)d_ws + OFF_X16);
  _Float16* act   = (_Float16*)((char*)d_ws + OFF_ACT);
  _Float16* gup16 = (_Float16*)((char*)d_ws + OFF_GUP16);
  _Float16* dp16  = (_Float16*)((char*)d_ws + OFF_DP16);

  hipMemsetAsync(d_out, 0, (size_t)NT * NH * sizeof(float), stream);
  hipMemsetAsync(d_ws, 0, 512, stream);

  bool pre = ws_size >= WS_NEED;
  if (pre) {
    convert_w<<<2048, 256, 0, stream>>>(gup, gup16, NE*2*NI*NH/8);
    convert_w<<<2048, 256, 0, stream>>>(dp,  dp16,  NE*NH*NI/8);
  }

  moe_router<<<NT / 4, 256, 0, stream>>>(x, rw, iws, x16);
  moe_scan<<<1, 64, 0, stream>>>(iws);
  moe_fill<<<NT / 256, 256, 0, stream>>>(iws);

  dim3 g1(NT * 2 / BM + NE, NI / 128);  // 136 x 32
  dim3 g2(NT * 2 / BM + NE, NH / 128);  // 136 x 8
  if (pre) {
    moe_gemm1_f16<<<g1, 256, 0, stream>>>(x16, gup16, iws, act);
    moe_gemm2_f16<<<g2, 256, 0, stream>>>(act, dp16, iws, out);
  } else {
    moe_gemm1<<<g1, 256, 0, stream>>>(x16, gup, iws, act);
    moe_gemm2<<<g2, 256, 0, stream>>>(act, dp, iws, out);
  }
}